// Round 8
// baseline (444.147 us; speedup 1.0000x reference)
//
#include <hip/hip_runtime.h>

// Problem constants (fixed by the reference): B=8, LQ=LK=2048, D=64.
#define NB 8
#define LQ 2048
#define LK 2048
#define DD 64
#define QBLK 32

typedef unsigned short u16;
typedef short  bf16x8 __attribute__((ext_vector_type(8)));   // 8 bf16 in 4 VGPRs (MFMA A/B frag)
typedef float  f32x4  __attribute__((ext_vector_type(4)));   // MFMA C/D frag
typedef u16    u16x4  __attribute__((ext_vector_type(4)));
typedef u16    u16x8  __attribute__((ext_vector_type(8)));

#define MFMA16(a, b, c) __builtin_amdgcn_mfma_f32_16x16x32_bf16((a), (b), (c), 0, 0, 0)
#define LOG2E 1.44269504088896f

__device__ __forceinline__ u16 f2bf(float f) {
  unsigned u = __builtin_bit_cast(unsigned, f);
  u = u + 0x7FFFu + ((u >> 16) & 1u);   // RNE
  return (u16)(u >> 16);
}

__device__ __forceinline__ float fexp2(float x) {   // 2^x -> one v_exp_f32
#if __has_builtin(__builtin_amdgcn_exp2f)
  return __builtin_amdgcn_exp2f(x);
#else
  return __builtin_exp2f(x);
#endif
}
__device__ __forceinline__ float flog2(float x) {   // log2 -> one v_log_f32
#if __has_builtin(__builtin_amdgcn_logf)
  return __builtin_amdgcn_logf(x);
#else
  return __builtin_log2f(x);
#endif
}

// ---------------------------------------------------------------------------
// Probe: determine the on-device layout of the boolean mask.
// ---------------------------------------------------------------------------
__global__ void probe_mask(const unsigned int* __restrict__ m, int* __restrict__ flags) {
  __shared__ int ff, fi, fo;
  if (threadIdx.x == 0) { ff = 0; fi = 0; fo = 0; }
  __syncthreads();
  int lf = 0, li = 0, lo = 0;
  for (int i = threadIdx.x; i < 16384; i += 256) {   // first 64KB
    unsigned wv = m[i];
    if (wv == 0x3F800000u) lf = 1;            // float 1.0f
    if (wv & 0xFFFFFF00u) li = 1;             // nonzero byte at off%4!=0 -> u8
    if (wv && (i & 1)) lo = 1;                // odd dword nonzero -> not int64
  }
  if (lf) atomicOr(&ff, 1);
  if (li) atomicOr(&fi, 1);
  if (lo) atomicOr(&fo, 1);
  __syncthreads();
  if (threadIdx.x == 0) {
    int shift, boff;
    if (ff)      { shift = 2; boff = 2; }     // f32: byte 2 of 1.0f is 0x80
    else if (fi) { shift = 0; boff = 0; }     // u8/bool
    else if (fo) { shift = 2; boff = 0; }     // int32
    else         { shift = 3; boff = 0; }     // int64
    flags[0] = shift; flags[1] = boff;
  }
}

// ---------------------------------------------------------------------------
// Prep: K -> Kbf (bf16 row-major), V -> Vt (bf16 transposed [b][d][k]).
// ---------------------------------------------------------------------------
__global__ __launch_bounds__(256) void prep_kv(
    const float* __restrict__ kf, const float* __restrict__ vf,
    u16* __restrict__ kbf, u16* __restrict__ vt) {
  __shared__ u16 tile[64][65];
  const int b = blockIdx.x >> 5;
  const int k0 = (blockIdx.x & 31) * 64;
  const int tid = threadIdx.x;
#pragma unroll
  for (int pass = 0; pass < 4; ++pass) {
    const int r = pass * 16 + (tid >> 4);
    const int c = (tid & 15) * 4;
    const size_t gi = ((size_t)(b * LK + k0 + r)) * DD + c;
    float4 kx = *(const float4*)(kf + gi);
    u16x4 kv = { f2bf(kx.x), f2bf(kx.y), f2bf(kx.z), f2bf(kx.w) };
    *(u16x4*)(kbf + gi) = kv;
    float4 vx = *(const float4*)(vf + gi);
    tile[r][c + 0] = f2bf(vx.x); tile[r][c + 1] = f2bf(vx.y);
    tile[r][c + 2] = f2bf(vx.z); tile[r][c + 3] = f2bf(vx.w);
  }
  __syncthreads();
  const int d = tid >> 2, kl = (tid & 3) * 16;
  u16 o[16];
#pragma unroll
  for (int j = 0; j < 16; ++j) o[j] = tile[kl + j][d];
  const size_t base = ((size_t)(b * DD + d)) * LK + k0 + kl;
  u16x8 o0 = { o[0], o[1], o[2], o[3], o[4], o[5], o[6], o[7] };
  u16x8 o1 = { o[8], o[9], o[10], o[11], o[12], o[13], o[14], o[15] };
  *(u16x8*)(vt + base) = o0;
  *(u16x8*)(vt + base + 8) = o1;
}

// ---------------------------------------------------------------------------
// Main kernel, 3-pass recompute softmax.  One block = 32 q-rows of one batch;
// 8 waves; wave w owns K cols [w*256, w*256+256).  QK^T is recomputed per pass
// (MFMA is ~2% utilized; registers are the scarce resource).  Mask is read
// once (pass 1a) and bit-packed.  P goes f32 through swizzled LDS so the
// 134MB attention write is full-128B-line nontemporal dwordx4.
// Target: <=128 total regs/wave -> 2 blocks/CU -> all 512 blocks co-resident.
// ---------------------------------------------------------------------------
__global__ __launch_bounds__(512, 4) void attn_main(
    const float* __restrict__ q, const u16* __restrict__ kbf,
    const u16* __restrict__ vt, const float* __restrict__ scale_p,
    const unsigned char* __restrict__ mask, const int* __restrict__ flags,
    float* __restrict__ ctx_out, float* __restrict__ attn_out) {
  // 32KB pool: per-wave P chunk [32 rows][32 cols] f32 (XOR-swizzled).
  // Reduction arrays + ctx accumulator alias the same pool (barrier-fenced).
  __shared__ float smem[8][1024];
  float* redmax = &smem[0][0];        // 256 floats
  float* redsum = redmax + 256;       // 256 floats
  float* ctxa   = redsum + 256;       // 2048 floats (32 rows x 64)

  const int bid = blockIdx.x;
  const int b = bid & 7;                  // batch -> XCD pinned (bid%8)
  const int q0 = (bid >> 3) * QBLK;
  const int tid = threadIdx.x;
  const int w = tid >> 6;
  const int lane = tid & 63;
  const int lg = lane >> 4, lr = lane & 15;
  const int k0w = w * 256;
  const float scl2 = scale_p[0] * LOG2E;  // fold log2(e) into Q scale
  const int mshift = flags[0], mboff = flags[1];

  // ---- Q A-fragments (scale*log2e folded into the bf16 conversion) ----
  bf16x8 aq[2][2];
#pragma unroll
  for (int mm = 0; mm < 2; ++mm)
#pragma unroll
    for (int c = 0; c < 2; ++c) {
      const float* qp = q + ((size_t)(b * LQ + q0 + mm * 16 + lr)) * DD + c * 32 + lg * 8;
      float4 x0 = *(const float4*)qp;
      float4 x1 = *(const float4*)(qp + 4);
      bf16x8 a;
      a[0] = (short)f2bf(x0.x * scl2); a[1] = (short)f2bf(x0.y * scl2);
      a[2] = (short)f2bf(x0.z * scl2); a[3] = (short)f2bf(x0.w * scl2);
      a[4] = (short)f2bf(x1.x * scl2); a[5] = (short)f2bf(x1.y * scl2);
      a[6] = (short)f2bf(x1.z * scl2); a[7] = (short)f2bf(x1.w * scl2);
      aq[mm][c] = a;
    }

  const u16* kb = kbf + (size_t)b * LK * DD;
  const size_t mrowbase = (size_t)b * LQ + q0;

  // ---- pass 1a: row max + mask bit-pack (mask read ONCE) ----
  // S layout per t: row = mm*16+lg*4+r, col = k0w + t*16 + lr.
  float m[2][4];
  unsigned mb[4] = {0u, 0u, 0u, 0u};     // (mm*4+r) -> half of mb[idx>>1]
#pragma unroll
  for (int mm = 0; mm < 2; ++mm)
#pragma unroll
    for (int r = 0; r < 4; ++r) m[mm][r] = -3.0e38f;

#pragma unroll
  for (int t = 0; t < 16; ++t) {
    const u16* kp = kb + (size_t)(k0w + t * 16 + lr) * DD + lg * 8;
    bf16x8 k0v = *(const bf16x8*)kp;
    bf16x8 k1v = *(const bf16x8*)(kp + 32);
    f32x4 z = { 0.f, 0.f, 0.f, 0.f };
    f32x4 a0 = z, a1 = z;
    a0 = MFMA16(aq[0][0], k0v, a0); a0 = MFMA16(aq[0][1], k1v, a0);
    a1 = MFMA16(aq[1][0], k0v, a1); a1 = MFMA16(aq[1][1], k1v, a1);
#pragma unroll
    for (int mm = 0; mm < 2; ++mm)
#pragma unroll
      for (int r = 0; r < 4; ++r) {
        const int row = mm * 16 + lg * 4 + r;
        const unsigned char mv = __builtin_nontemporal_load(
            mask + ((((mrowbase + row) * LK) + k0w + t * 16 + lr) << mshift) + mboff);
        const int idx = mm * 4 + r;
        mb[idx >> 1] |= (mv ? 1u : 0u) << (((idx & 1) << 4) + t);
        float v = mm ? a1[r] : a0[r];
        v = mv ? -3.0e38f : v;
        m[mm][r] = fmaxf(m[mm][r], v);
      }
  }
  // reduce max: 16 lanes sharing each row, then across 8 waves via LDS
#pragma unroll
  for (int mm = 0; mm < 2; ++mm)
#pragma unroll
    for (int r = 0; r < 4; ++r) {
      float mx = m[mm][r];
      mx = fmaxf(mx, __shfl_xor(mx, 1));
      mx = fmaxf(mx, __shfl_xor(mx, 2));
      mx = fmaxf(mx, __shfl_xor(mx, 4));
      mx = fmaxf(mx, __shfl_xor(mx, 8));
      m[mm][r] = mx;
    }
  if (lr == 0) {
#pragma unroll
    for (int mm = 0; mm < 2; ++mm)
#pragma unroll
      for (int r = 0; r < 4; ++r) redmax[w * 32 + mm * 16 + lg * 4 + r] = m[mm][r];
  }
  __syncthreads();   // B1
#pragma unroll
  for (int mm = 0; mm < 2; ++mm)
#pragma unroll
    for (int r = 0; r < 4; ++r) {
      const int row = mm * 16 + lg * 4 + r;
      float mx = redmax[row];
#pragma unroll
      for (int w2 = 1; w2 < 8; ++w2) mx = fmaxf(mx, redmax[w2 * 32 + row]);
      m[mm][r] = mx;   // block-wide row max (in log2e units)
    }

  // ---- pass 1b: recompute QK^T, accumulate sum of 2^(v-m) ----
  float sac[2][4];
#pragma unroll
  for (int mm = 0; mm < 2; ++mm)
#pragma unroll
    for (int r = 0; r < 4; ++r) sac[mm][r] = 0.f;
#pragma unroll
  for (int t = 0; t < 16; ++t) {
    const u16* kp = kb + (size_t)(k0w + t * 16 + lr) * DD + lg * 8;
    bf16x8 k0v = *(const bf16x8*)kp;
    bf16x8 k1v = *(const bf16x8*)(kp + 32);
    f32x4 z = { 0.f, 0.f, 0.f, 0.f };
    f32x4 a0 = z, a1 = z;
    a0 = MFMA16(aq[0][0], k0v, a0); a0 = MFMA16(aq[0][1], k1v, a0);
    a1 = MFMA16(aq[1][0], k0v, a1); a1 = MFMA16(aq[1][1], k1v, a1);
#pragma unroll
    for (int mm = 0; mm < 2; ++mm)
#pragma unroll
      for (int r = 0; r < 4; ++r) {
        const int idx = mm * 4 + r;
        const unsigned bit = (mb[idx >> 1] >> (((idx & 1) << 4) + t)) & 1u;
        float v = mm ? a1[r] : a0[r];
        float e = fexp2(v - m[mm][r]);
        e = bit ? 0.f : e;
        sac[mm][r] += e;
      }
  }
#pragma unroll
  for (int mm = 0; mm < 2; ++mm)
#pragma unroll
    for (int r = 0; r < 4; ++r) {
      float s = sac[mm][r];
      s += __shfl_xor(s, 1);
      s += __shfl_xor(s, 2);
      s += __shfl_xor(s, 4);
      s += __shfl_xor(s, 8);
      sac[mm][r] = s;
    }
  if (lr == 0) {
#pragma unroll
    for (int mm = 0; mm < 2; ++mm)
#pragma unroll
      for (int r = 0; r < 4; ++r) redsum[w * 32 + mm * 16 + lg * 4 + r] = sac[mm][r];
  }
  __syncthreads();   // B2
  // c = m + log2(sum): p = 2^(v - c) is the normalized softmax value
  float cc[2][4];
#pragma unroll
  for (int mm = 0; mm < 2; ++mm)
#pragma unroll
    for (int r = 0; r < 4; ++r) {
      const int row = mm * 16 + lg * 4 + r;
      float s = redsum[row];
#pragma unroll
      for (int w2 = 1; w2 < 8; ++w2) s += redsum[w2 * 32 + row];
      cc[mm][r] = m[mm][r] + flog2(s);
    }
  __syncthreads();   // B3: reduction arrays dead; P chunks may now overwrite pool

  // ---- pass 2: recompute per kk (32 cols), emit P + attention + PV ----
  f32x4 cacc[2][4];
#pragma unroll
  for (int mm = 0; mm < 2; ++mm)
#pragma unroll
    for (int dd = 0; dd < 4; ++dd) {
      f32x4 z = { 0.f, 0.f, 0.f, 0.f };
      cacc[mm][dd] = z;
    }
  float* pbw = smem[w];
  const u16* vtb = vt + (size_t)b * DD * LK;
  float* attb = attn_out + mrowbase * LK;

#pragma unroll
  for (int kk = 0; kk < 8; ++kk) {
    f32x4 a[2][2];   // [mm][tt]
#pragma unroll
    for (int tt = 0; tt < 2; ++tt) {
      const int t = kk * 2 + tt;
      const u16* kp = kb + (size_t)(k0w + t * 16 + lr) * DD + lg * 8;
      bf16x8 k0v = *(const bf16x8*)kp;
      bf16x8 k1v = *(const bf16x8*)(kp + 32);
      f32x4 z = { 0.f, 0.f, 0.f, 0.f };
      f32x4 a0 = z, a1 = z;
      a0 = MFMA16(aq[0][0], k0v, a0); a0 = MFMA16(aq[0][1], k1v, a0);
      a1 = MFMA16(aq[1][0], k0v, a1); a1 = MFMA16(aq[1][1], k1v, a1);
      a[0][tt] = a0; a[1][tt] = a1;
    }
    // normalized P -> swizzled LDS (f32)
#pragma unroll
    for (int mm = 0; mm < 2; ++mm)
#pragma unroll
      for (int tt = 0; tt < 2; ++tt)
#pragma unroll
        for (int r = 0; r < 4; ++r) {
          const int t = kk * 2 + tt;
          const int idx = mm * 4 + r;
          const unsigned bit = (mb[idx >> 1] >> (((idx & 1) << 4) + t)) & 1u;
          float p = fexp2(a[mm][tt][r] - cc[mm][r]);
          p = bit ? 0.f : p;
          const int row = mm * 16 + lg * 4 + r;
          const int off = (row * 128 + (tt * 16 + lr) * 4) ^ ((row & 7) << 4);
          *(float*)((char*)pbw + off) = p;
        }
    asm volatile("s_waitcnt lgkmcnt(0)" ::: "memory");
    __builtin_amdgcn_sched_barrier(0);
    // attention store: full-line 16B nontemporal, 32 rows x 32 cols per wave
#pragma unroll
    for (int pp = 0; pp < 4; ++pp) {
      const int row = pp * 8 + (lane >> 3);
      const int c4 = (lane & 7) * 4;
      const int off = (row * 128 + c4 * 4) ^ ((row & 7) << 4);
      f32x4 val = *(const f32x4*)((const char*)pbw + off);
      __builtin_nontemporal_store(val, (f32x4*)(attb + (size_t)row * LK + k0w + kk * 32 + c4));
    }
    // PV: A-frag from LDS (f32 -> bf16), B-frag = Vt 16B loads (L2-hot)
    bf16x8 pa[2];
#pragma unroll
    for (int mm = 0; mm < 2; ++mm) {
      const int row = mm * 16 + lr;
      const int swz = (row & 7) << 4;
      f32x4 f0 = *(const f32x4*)((const char*)pbw + ((row * 128 + lg * 32) ^ swz));
      f32x4 f1 = *(const f32x4*)((const char*)pbw + ((row * 128 + lg * 32 + 16) ^ swz));
      bf16x8 pv;
      pv[0] = (short)f2bf(f0[0]); pv[1] = (short)f2bf(f0[1]);
      pv[2] = (short)f2bf(f0[2]); pv[3] = (short)f2bf(f0[3]);
      pv[4] = (short)f2bf(f1[0]); pv[5] = (short)f2bf(f1[1]);
      pv[6] = (short)f2bf(f1[2]); pv[7] = (short)f2bf(f1[3]);
      pa[mm] = pv;
    }
#pragma unroll
    for (int dd = 0; dd < 4; ++dd) {
      const u16* vp = vtb + (size_t)(dd * 16 + lr) * LK + k0w + kk * 32 + lg * 8;
      bf16x8 vb = *(const bf16x8*)vp;
      cacc[0][dd] = MFMA16(pa[0], vb, cacc[0][dd]);
      cacc[1][dd] = MFMA16(pa[1], vb, cacc[1][dd]);
    }
  }

  // ---- cross-wave context reduction (ctxa aliases the pool) + store ----
  __syncthreads();   // B4: all P-chunk reads done
  {
    float* cz = ctxa;
#pragma unroll
    for (int i = 0; i < 4; ++i) cz[tid + i * 512] = 0.f;
  }
  __syncthreads();   // B5
#pragma unroll
  for (int mm = 0; mm < 2; ++mm)
#pragma unroll
    for (int dd = 0; dd < 4; ++dd)
#pragma unroll
      for (int r = 0; r < 4; ++r)
        atomicAdd(&ctxa[(mm * 16 + lg * 4 + r) * DD + dd * 16 + lr], cacc[mm][dd][r]);
  __syncthreads();   // B6
  {
    const int row = tid >> 4, d0 = (tid & 15) * 4;
    f32x4 val = *(const f32x4*)&ctxa[row * DD + d0];
    __builtin_nontemporal_store(val, (f32x4*)(ctx_out + ((size_t)(b * LQ) + q0 + row) * DD + d0));
  }
}

// ---------------------------------------------------------------------------
// Naive fallback (only if ws_size is too small for the staging buffers).
// ---------------------------------------------------------------------------
__global__ __launch_bounds__(64) void attn_naive(
    const float* __restrict__ q, const float* __restrict__ kf,
    const float* __restrict__ vf, const float* __restrict__ scale_p,
    const unsigned char* __restrict__ mask, const int* __restrict__ flags,
    float* __restrict__ ctx_out, float* __restrict__ attn_out) {
  __shared__ float red[64][65];
  const int row = blockIdx.x;             // b*LQ + qr
  const int lane = threadIdx.x;
  const int shift = flags[0], boff = flags[1];
  const float scl = scale_p[0];
  const int b = row >> 11;
  float qv[DD];
#pragma unroll
  for (int d = 0; d < DD; ++d) qv[d] = q[(size_t)row * DD + d] * scl;
  float s[32];
  float mx = -3.0e38f;
#pragma unroll
  for (int i = 0; i < 32; ++i) {
    const int kc = lane + i * 64;
    const float* kp = kf + ((size_t)b * LK + kc) * DD;
    float dot = 0.f;
#pragma unroll
    for (int d = 0; d < DD; ++d) dot = fmaf(qv[d], kp[d], dot);
    const unsigned char mv = mask[((((size_t)row) * LK + kc) << shift) + boff];
    dot = mv ? -1.0e30f : dot;
    s[i] = dot;
    mx = fmaxf(mx, dot);
  }
#pragma unroll
  for (int off = 32; off; off >>= 1) mx = fmaxf(mx, __shfl_xor(mx, off));
  float sum = 0.f;
#pragma unroll
  for (int i = 0; i < 32; ++i) { s[i] = __expf(s[i] - mx); sum += s[i]; }
#pragma unroll
  for (int off = 32; off; off >>= 1) sum += __shfl_xor(sum, off);
  const float rl = 1.0f / sum;
  float cl[DD];
#pragma unroll
  for (int d = 0; d < DD; ++d) cl[d] = 0.f;
#pragma unroll
  for (int i = 0; i < 32; ++i) {
    const int kc = lane + i * 64;
    const float p = s[i] * rl;
    attn_out[(size_t)row * LK + kc] = p;
    const float* vp = vf + ((size_t)b * LK + kc) * DD;
#pragma unroll
    for (int d = 0; d < DD; ++d) cl[d] = fmaf(p, vp[d], cl[d]);
  }
#pragma unroll
  for (int d = 0; d < DD; ++d) red[lane][d] = cl[d];
  __syncthreads();
  float o = 0.f;
#pragma unroll
  for (int j = 0; j < 64; ++j) o += red[j][lane];
  ctx_out[(size_t)row * DD + lane] = o;
}

// ---------------------------------------------------------------------------
extern "C" void kernel_launch(void* const* d_in, const int* in_sizes, int n_in,
                              void* d_out, int out_size, void* d_ws, size_t ws_size,
                              hipStream_t stream) {
  const float* q  = (const float*)d_in[0];
  const float* kf = (const float*)d_in[1];
  const float* vf = (const float*)d_in[2];
  const float* sc = (const float*)d_in[3];
  const unsigned char* mask = (const unsigned char*)d_in[4];
  float* ctx  = (float*)d_out;
  float* attn = ctx + (size_t)NB * LQ * DD;

  int* flags = (int*)d_ws;
  const size_t kv_elems = (size_t)NB * LK * DD;            // 1,048,576
  const size_t need = 1024 + 2 * kv_elems * sizeof(u16);   // flags + Kbf + Vt (~4MB)

  hipLaunchKernelGGL(probe_mask, dim3(1), dim3(256), 0, stream,
                     (const unsigned int*)mask, flags);

  if (ws_size >= need) {
    u16* kbf = (u16*)((char*)d_ws + 1024);
    u16* vt  = kbf + kv_elems;
    hipLaunchKernelGGL(prep_kv, dim3(NB * 32), dim3(256), 0, stream, kf, vf, kbf, vt);
    hipLaunchKernelGGL(attn_main, dim3((LQ / QBLK) * NB), dim3(512), 0, stream,
                       q, kbf, vt, sc, mask, flags, ctx, attn);
  } else {
    hipLaunchKernelGGL(attn_naive, dim3(NB * LQ), dim3(64), 0, stream,
                       q, kf, vf, sc, mask, flags, ctx, attn);
  }
}

// Round 10
// 326.189 us; speedup vs baseline: 1.3616x; 1.3616x over previous
//
#include <hip/hip_runtime.h>

// Problem constants (fixed by the reference): B=8, LQ=LK=2048, D=64.
#define NB 8
#define LQ 2048
#define LK 2048
#define DD 64
#define QBLK 16

typedef unsigned short u16;
typedef short  bf16x8 __attribute__((ext_vector_type(8)));   // 8 bf16 in 4 VGPRs (MFMA A/B frag)
typedef float  f32x4  __attribute__((ext_vector_type(4)));   // MFMA C/D frag
typedef u16    u16x4  __attribute__((ext_vector_type(4)));
typedef u16    u16x8  __attribute__((ext_vector_type(8)));

#define MFMA16(a, b, c) __builtin_amdgcn_mfma_f32_16x16x32_bf16((a), (b), (c), 0, 0, 0)
#define LOG2E 1.44269504088896f

__device__ __forceinline__ u16 f2bf(float f) {
  unsigned u = __builtin_bit_cast(unsigned, f);
  u = u + 0x7FFFu + ((u >> 16) & 1u);   // RNE
  return (u16)(u >> 16);
}

__device__ __forceinline__ float fexp2(float x) {   // 2^x -> one v_exp_f32
#if __has_builtin(__builtin_amdgcn_exp2f)
  return __builtin_amdgcn_exp2f(x);
#else
  return __builtin_exp2f(x);
#endif
}

// ---------------------------------------------------------------------------
// Probe: determine the on-device layout of the boolean mask (4KB scan).
// ---------------------------------------------------------------------------
__global__ void probe_mask(const unsigned int* __restrict__ m, int* __restrict__ flags) {
  __shared__ int ff, fi, fo;
  if (threadIdx.x == 0) { ff = 0; fi = 0; fo = 0; }
  __syncthreads();
  int lf = 0, li = 0, lo = 0;
  for (int i = threadIdx.x; i < 1024; i += 256) {   // first 4KB
    unsigned wv = m[i];
    if (wv == 0x3F800000u) lf = 1;            // float 1.0f
    if (wv & 0xFFFFFF00u) li = 1;             // nonzero byte off%4!=0 -> u8
    if (wv && (i & 1)) lo = 1;                // odd dword nonzero -> not int64
  }
  if (lf) atomicOr(&ff, 1);
  if (li) atomicOr(&fi, 1);
  if (lo) atomicOr(&fo, 1);
  __syncthreads();
  if (threadIdx.x == 0) {
    int shift, boff;
    if (ff)      { shift = 2; boff = 2; }     // f32: byte 2 of 1.0f is 0x80
    else if (fi) { shift = 0; boff = 0; }     // u8/bool
    else if (fo) { shift = 2; boff = 0; }     // int32
    else         { shift = 3; boff = 0; }     // int64
    flags[0] = shift; flags[1] = boff;
  }
}

// ---------------------------------------------------------------------------
// Prep: K -> Kbf (bf16 row-major), V -> Vt (bf16 transposed [b][d][k]).
// ---------------------------------------------------------------------------
__global__ __launch_bounds__(256) void prep_kv(
    const float* __restrict__ kf, const float* __restrict__ vf,
    u16* __restrict__ kbf, u16* __restrict__ vt) {
  __shared__ u16 tile[64][65];
  const int b = blockIdx.x >> 5;
  const int k0 = (blockIdx.x & 31) * 64;
  const int tid = threadIdx.x;
#pragma unroll
  for (int pass = 0; pass < 4; ++pass) {
    const int r = pass * 16 + (tid >> 4);
    const int c = (tid & 15) * 4;
    const size_t gi = ((size_t)(b * LK + k0 + r)) * DD + c;
    float4 kx = *(const float4*)(kf + gi);
    u16x4 kv = { f2bf(kx.x), f2bf(kx.y), f2bf(kx.z), f2bf(kx.w) };
    *(u16x4*)(kbf + gi) = kv;
    float4 vx = *(const float4*)(vf + gi);
    tile[r][c + 0] = f2bf(vx.x); tile[r][c + 1] = f2bf(vx.y);
    tile[r][c + 2] = f2bf(vx.z); tile[r][c + 3] = f2bf(vx.w);
  }
  __syncthreads();
  const int d = tid >> 2, kl = (tid & 3) * 16;
  u16 o[16];
#pragma unroll
  for (int j = 0; j < 16; ++j) o[j] = tile[kl + j][d];
  const size_t base = ((size_t)(b * DD + d)) * LK + k0 + kl;
  u16x8 o0 = { o[0], o[1], o[2], o[3], o[4], o[5], o[6], o[7] };
  u16x8 o1 = { o[8], o[9], o[10], o[11], o[12], o[13], o[14], o[15] };
  *(u16x8*)(vt + base) = o0;
  *(u16x8*)(vt + base + 8) = o1;
}

// ---------------------------------------------------------------------------
// Main kernel: 1-pass, S held in registers (round-3 structure = clean traffic)
// with QBLK=16 for occupancy (acc slab halved to 64 VGPR -> ~120 total ->
// 4 waves/SIMD, 2 blocks/CU, 1024 blocks).  One block = 16 q-rows of one
// batch; 8 waves; wave w owns K cols [w*256, w*256+256).  Mask read once,
// folded into acc.  Plain cached stores ONLY (round-8's nontemporal stores
// caused +220MB write amplification + L2 thrash -> reverted).
// ---------------------------------------------------------------------------
__global__ __launch_bounds__(512, 4) void attn_main(
    const float* __restrict__ q, const u16* __restrict__ kbf,
    const u16* __restrict__ vt, const float* __restrict__ scale_p,
    const unsigned char* __restrict__ mask, const int* __restrict__ flags,
    float* __restrict__ ctx_out, float* __restrict__ attn_out) {
  __shared__ float redmax[8][16];
  __shared__ float redsum[8][16];
  __shared__ float ctxa[QBLK][DD];   // 4KB
  __shared__ u16 pb[8][1024];        // per-wave 2KB: 16 rows x 128B, XOR-swizzled
                                     // (byte-identical swizzle to round-3's
                                     //  measured-0-conflict layout)

  const int bid = blockIdx.x;
  const int b = bid & 7;                  // batch -> XCD pinned (bid%8)
  const int q0 = (bid >> 3) * QBLK;
  const int tid = threadIdx.x;
  const int w = tid >> 6;
  const int lane = tid & 63;
  const int lg = lane >> 4, lr = lane & 15;
  const int k0w = w * 256;
  const float scl2 = scale_p[0] * LOG2E;  // fold log2(e): softmax via exp2
  const int mshift = flags[0], mboff = flags[1];

  // zero context accumulator (first use is after barrier B1)
  {
    float* cz = &ctxa[0][0];
    for (int i = tid; i < QBLK * DD; i += 512) cz[i] = 0.f;
  }

  // ---- Q A-fragments: rows q0+lr, scale*log2e folded into bf16 convert ----
  bf16x8 aq[2];
#pragma unroll
  for (int c = 0; c < 2; ++c) {
    const float* qp = q + ((size_t)(b * LQ + q0 + lr)) * DD + c * 32 + lg * 8;
    float4 x0 = *(const float4*)qp;
    float4 x1 = *(const float4*)(qp + 4);
    bf16x8 a;
    a[0] = (short)f2bf(x0.x * scl2); a[1] = (short)f2bf(x0.y * scl2);
    a[2] = (short)f2bf(x0.z * scl2); a[3] = (short)f2bf(x0.w * scl2);
    a[4] = (short)f2bf(x1.x * scl2); a[5] = (short)f2bf(x1.y * scl2);
    a[6] = (short)f2bf(x1.z * scl2); a[7] = (short)f2bf(x1.w * scl2);
    aq[c] = a;
  }

  // ---- QK^T: acc[t][r] = S[q-row = lg*4+r][key = k0w + t*16 + lr] ----
  f32x4 acc[16];
#pragma unroll
  for (int t = 0; t < 16; ++t) {
    f32x4 z = { 0.f, 0.f, 0.f, 0.f };
    acc[t] = z;
  }
  const u16* kb = kbf + (size_t)b * LK * DD;
#pragma unroll
  for (int t = 0; t < 16; ++t) {
    const u16* kp = kb + (size_t)(k0w + t * 16 + lr) * DD + lg * 8;
    bf16x8 k0v = *(const bf16x8*)kp;
    bf16x8 k1v = *(const bf16x8*)(kp + 32);
    acc[t] = MFMA16(aq[0], k0v, acc[t]);
    acc[t] = MFMA16(aq[1], k1v, acc[t]);
  }

  // ---- mask (read once, fold into acc) + per-lane row max ----
  const size_t mrowbase = (size_t)b * LQ + q0;
  float rmax[4];
#pragma unroll
  for (int r = 0; r < 4; ++r) {
    const int row = lg * 4 + r;
    const unsigned char* mrow = mask + (((mrowbase + row) * LK) << mshift) + mboff;
    float mx = -3.0e38f;
#pragma unroll
    for (int t = 0; t < 16; ++t) {
      const unsigned char mv = mrow[((size_t)(k0w + t * 16 + lr)) << mshift];
      float s = acc[t][r];
      s = mv ? -3.0e38f : s;
      acc[t][r] = s;
      mx = fmaxf(mx, s);
    }
    rmax[r] = mx;
  }
  // reduce max: 16 lanes sharing each row, then across 8 waves via LDS
#pragma unroll
  for (int r = 0; r < 4; ++r) {
    float mx = rmax[r];
    mx = fmaxf(mx, __shfl_xor(mx, 1));
    mx = fmaxf(mx, __shfl_xor(mx, 2));
    mx = fmaxf(mx, __shfl_xor(mx, 4));
    mx = fmaxf(mx, __shfl_xor(mx, 8));
    rmax[r] = mx;
  }
  if (lr == 0) {
#pragma unroll
    for (int r = 0; r < 4; ++r) redmax[w][lg * 4 + r] = rmax[r];
  }
  __syncthreads();   // B1
  float fm[4];
#pragma unroll
  for (int r = 0; r < 4; ++r) {
    const int row = lg * 4 + r;
    float mx = redmax[0][row];
#pragma unroll
    for (int w2 = 1; w2 < 8; ++w2) mx = fmaxf(mx, redmax[w2][row]);
    fm[r] = mx;
  }

  // ---- exp2 (once, into acc) + row sum ----
  float rsum[4];
#pragma unroll
  for (int r = 0; r < 4; ++r) {
    float s = 0.f;
#pragma unroll
    for (int t = 0; t < 16; ++t) {
      float e = fexp2(acc[t][r] - fm[r]);   // masked: -3e38 - m -> exp2 -> 0
      acc[t][r] = e;
      s += e;
    }
    rsum[r] = s;
  }
#pragma unroll
  for (int r = 0; r < 4; ++r) {
    float s = rsum[r];
    s += __shfl_xor(s, 1);
    s += __shfl_xor(s, 2);
    s += __shfl_xor(s, 4);
    s += __shfl_xor(s, 8);
    rsum[r] = s;
  }
  if (lr == 0) {
#pragma unroll
    for (int r = 0; r < 4; ++r) redsum[w][lg * 4 + r] = rsum[r];
  }
  __syncthreads();   // B2
  float rl[4];
#pragma unroll
  for (int r = 0; r < 4; ++r) {
    const int row = lg * 4 + r;
    float s = redsum[0][row];
#pragma unroll
    for (int w2 = 1; w2 < 8; ++w2) s += redsum[w2][row];
    rl[r] = 1.0f / s;
  }

  // ---- emit: normalize from regs, plain f32 attn store, PV via LDS bf16 ----
  f32x4 cacc[4];
#pragma unroll
  for (int dd = 0; dd < 4; ++dd) {
    f32x4 z = { 0.f, 0.f, 0.f, 0.f };
    cacc[dd] = z;
  }
  u16* pbw = pb[w];
  const u16* vtb = vt + (size_t)b * DD * LK;
  float* attb = attn_out + mrowbase * LK;

#pragma unroll
  for (int kk = 0; kk < 8; ++kk) {
#pragma unroll
    for (int tt = 0; tt < 2; ++tt) {
      const int t = kk * 2 + tt;
#pragma unroll
      for (int r = 0; r < 4; ++r) {
        const int row = lg * 4 + r;
        float p = acc[t][r] * rl[r];
        attb[(size_t)row * LK + k0w + t * 16 + lr] = p;   // plain cached store
        const int off = (row * 128 + (tt * 16 + lr) * 2) ^ ((row & 7) << 4);
        *(u16*)((char*)pbw + off) = f2bf(p);
      }
    }
    asm volatile("s_waitcnt lgkmcnt(0)" ::: "memory");
    __builtin_amdgcn_sched_barrier(0);
    bf16x8 pa;
    {
      const int ro = (lr * 128 + lg * 16) ^ ((lr & 7) << 4);
      pa = *(const bf16x8*)((const char*)pbw + ro);
    }
#pragma unroll
    for (int dd = 0; dd < 4; ++dd) {
      const u16* vp = vtb + (size_t)(dd * 16 + lr) * LK + k0w + kk * 32 + lg * 8;
      bf16x8 vb = *(const bf16x8*)vp;
      cacc[dd] = MFMA16(pa, vb, cacc[dd]);
    }
  }

  // ---- cross-wave context reduction + store ----
#pragma unroll
  for (int dd = 0; dd < 4; ++dd)
#pragma unroll
    for (int r = 0; r < 4; ++r)
      atomicAdd(&ctxa[lg * 4 + r][dd * 16 + lr], cacc[dd][r]);
  __syncthreads();   // B3
  if (tid < QBLK * 16) {
    const int row = tid >> 4, d0 = (tid & 15) * 4;
    float4 val = *(const float4*)&ctxa[row][d0];
    *(float4*)(ctx_out + ((size_t)(b * LQ) + q0 + row) * DD + d0) = val;
  }
}

// ---------------------------------------------------------------------------
// Naive fallback (only if ws_size is too small for the staging buffers).
// ---------------------------------------------------------------------------
__global__ __launch_bounds__(64) void attn_naive(
    const float* __restrict__ q, const float* __restrict__ kf,
    const float* __restrict__ vf, const float* __restrict__ scale_p,
    const unsigned char* __restrict__ mask, const int* __restrict__ flags,
    float* __restrict__ ctx_out, float* __restrict__ attn_out) {
  __shared__ float red[64][65];
  const int row = blockIdx.x;             // b*LQ + qr
  const int lane = threadIdx.x;
  const int shift = flags[0], boff = flags[1];
  const float scl = scale_p[0];
  const int b = row >> 11;
  float qv[DD];
#pragma unroll
  for (int d = 0; d < DD; ++d) qv[d] = q[(size_t)row * DD + d] * scl;
  float s[32];
  float mx = -3.0e38f;
#pragma unroll
  for (int i = 0; i < 32; ++i) {
    const int kc = lane + i * 64;
    const float* kp = kf + ((size_t)b * LK + kc) * DD;
    float dot = 0.f;
#pragma unroll
    for (int d = 0; d < DD; ++d) dot = fmaf(qv[d], kp[d], dot);
    const unsigned char mv = mask[((((size_t)row) * LK + kc) << shift) + boff];
    dot = mv ? -1.0e30f : dot;
    s[i] = dot;
    mx = fmaxf(mx, dot);
  }
#pragma unroll
  for (int off = 32; off; off >>= 1) mx = fmaxf(mx, __shfl_xor(mx, off));
  float sum = 0.f;
#pragma unroll
  for (int i = 0; i < 32; ++i) { s[i] = __expf(s[i] - mx); sum += s[i]; }
#pragma unroll
  for (int off = 32; off; off >>= 1) sum += __shfl_xor(sum, off);
  const float rl = 1.0f / sum;
  float cl[DD];
#pragma unroll
  for (int d = 0; d < DD; ++d) cl[d] = 0.f;
#pragma unroll
  for (int i = 0; i < 32; ++i) {
    const int kc = lane + i * 64;
    const float p = s[i] * rl;
    attn_out[(size_t)row * LK + kc] = p;
    const float* vp = vf + ((size_t)b * LK + kc) * DD;
#pragma unroll
    for (int d = 0; d < DD; ++d) cl[d] = fmaf(p, vp[d], cl[d]);
  }
#pragma unroll
  for (int d = 0; d < DD; ++d) red[lane][d] = cl[d];
  __syncthreads();
  float o = 0.f;
#pragma unroll
  for (int j = 0; j < 64; ++j) o += red[j][lane];
  ctx_out[(size_t)row * DD + lane] = o;
}

// ---------------------------------------------------------------------------
extern "C" void kernel_launch(void* const* d_in, const int* in_sizes, int n_in,
                              void* d_out, int out_size, void* d_ws, size_t ws_size,
                              hipStream_t stream) {
  const float* q  = (const float*)d_in[0];
  const float* kf = (const float*)d_in[1];
  const float* vf = (const float*)d_in[2];
  const float* sc = (const float*)d_in[3];
  const unsigned char* mask = (const unsigned char*)d_in[4];
  float* ctx  = (float*)d_out;
  float* attn = ctx + (size_t)NB * LQ * DD;

  int* flags = (int*)d_ws;
  const size_t kv_elems = (size_t)NB * LK * DD;            // 1,048,576
  const size_t need = 1024 + 2 * kv_elems * sizeof(u16);   // flags + Kbf + Vt (~4MB)

  hipLaunchKernelGGL(probe_mask, dim3(1), dim3(256), 0, stream,
                     (const unsigned int*)mask, flags);

  if (ws_size >= need) {
    u16* kbf = (u16*)((char*)d_ws + 1024);
    u16* vt  = kbf + kv_elems;
    hipLaunchKernelGGL(prep_kv, dim3(NB * 32), dim3(256), 0, stream, kf, vf, kbf, vt);
    hipLaunchKernelGGL(attn_main, dim3((LQ / QBLK) * NB), dim3(512), 0, stream,
                       q, kbf, vt, sc, mask, flags, ctx, attn);
  } else {
    hipLaunchKernelGGL(attn_naive, dim3(NB * LQ), dim3(64), 0, stream,
                       q, kf, vf, sc, mask, flags, ctx, attn);
  }
}